// Round 1
// baseline (190.277 us; speedup 1.0000x reference)
//
#include <hip/hip_runtime.h>

// UniformKernel: per-column (dim) moving average (K=10, replicate pad) over
// bins axis + per-column normalization. densities: (NB=2048, DIM=32768) f32.
//
// out(b,d) = window_sum(b,d) / (width * sum_i w[i]*x[i,d])
// where w[i] = # windows covering row i under edge clamping (K cancels).

constexpr int NB   = 2048;
constexpr int DIM  = 32768;
constexpr int DIM4 = DIM / 4;

constexpr int RC1   = 32;        // pass-1 row chunks
constexpr int ROWS1 = NB / RC1;  // 64 rows per chunk
constexpr int RC2   = 16;        // pass-2 row chunks
constexpr int ROWS2 = NB / RC2;  // 128 rows per chunk

// Weight = number of K=10 windows (PAD_LEFT=4, PAD_RIGHT=5) covering source
// row i after replicate clamping. Interior = 10; head = 15,6,7,8,9;
// tail = 9,8,7,21. Verified: sum = NB*K = 20480.
__device__ __forceinline__ float wrow(int i) {
    int a = min(i + 4, NB - 1) - max(i - 5, 0) + 1;  // unclamped coverage
    if (i == 0)      a += 10;                        // clamped negative pads
    if (i == NB - 1) a += 15;                        // clamped over-pads
    return (float)a;
}

// Pass 1: partial weighted column sums. grid (DIM4/256, RC1), 256 thr.
// Fully coalesced: wave reads 1 KB contiguous per row.
__global__ __launch_bounds__(256) void k_colsum(const float* __restrict__ x,
                                                float* __restrict__ partial) {
    const int d4 = blockIdx.x * 256 + threadIdx.x;   // float4 column group
    const int r0 = blockIdx.y * ROWS1;
    const float4* __restrict__ px = reinterpret_cast<const float4*>(x) + d4;
    float ax = 0.f, ay = 0.f, az = 0.f, aw = 0.f;
    #pragma unroll 4
    for (int i = r0; i < r0 + ROWS1; ++i) {
        const float w = wrow(i);
        const float4 v = px[(size_t)i * DIM4];
        ax += w * v.x; ay += w * v.y; az += w * v.z; aw += w * v.w;
    }
    float4 acc; acc.x = ax; acc.y = ay; acc.z = az; acc.w = aw;
    reinterpret_cast<float4*>(partial)[(size_t)blockIdx.y * DIM4 + d4] = acc;
}

// Pass 1b: reduce partials, compute scale[d] = 1/(width * sum). grid 32x256.
__global__ __launch_bounds__(256) void k_scale(const float* __restrict__ partial,
                                               const float* __restrict__ bins,
                                               float* __restrict__ scale) {
    const int d4 = blockIdx.x * 256 + threadIdx.x;
    const float4* __restrict__ pp = reinterpret_cast<const float4*>(partial) + d4;
    float sx = 0.f, sy = 0.f, sz = 0.f, sw = 0.f;
    #pragma unroll
    for (int rc = 0; rc < RC1; ++rc) {
        const float4 v = pp[(size_t)rc * DIM4];
        sx += v.x; sy += v.y; sz += v.z; sw += v.w;
    }
    const float width = bins[1] - bins[0];
    float4 r;
    r.x = 1.f / (width * sx);
    r.y = 1.f / (width * sy);
    r.z = 1.f / (width * sz);
    r.w = 1.f / (width * sw);
    reinterpret_cast<float4*>(scale)[d4] = r;
}

// Pass 2: running window sum per thread (4 columns), normalized store.
// grid (DIM4/256, RC2), 256 thr. window(b+1) = window(b) + x[clamp(b+6)]
// - x[clamp(b-4)] holds exactly under replicate clamping.
__global__ __launch_bounds__(256) void k_smooth(const float* __restrict__ x,
                                                const float* __restrict__ scale,
                                                float* __restrict__ out) {
    const int d4 = blockIdx.x * 256 + threadIdx.x;
    const int b0 = blockIdx.y * ROWS2;
    const float4* __restrict__ px = reinterpret_cast<const float4*>(x) + d4;
    float4* __restrict__ po = reinterpret_cast<float4*>(out) + d4;
    const float4 sc = reinterpret_cast<const float4*>(scale)[d4];

    float sx = 0.f, sy = 0.f, sz = 0.f, sw = 0.f;
    #pragma unroll
    for (int m = 0; m < 10; ++m) {
        int j = b0 - 4 + m;
        j = min(max(j, 0), NB - 1);
        const float4 v = px[(size_t)j * DIM4];
        sx += v.x; sy += v.y; sz += v.z; sw += v.w;
    }
    for (int b = b0; b < b0 + ROWS2; ++b) {
        float4 o;
        o.x = sx * sc.x; o.y = sy * sc.y; o.z = sz * sc.z; o.w = sw * sc.w;
        po[(size_t)b * DIM4] = o;
        const int jn = min(b + 6, NB - 1);
        const int jo = max(b - 4, 0);
        const float4 vn = px[(size_t)jn * DIM4];
        const float4 vo = px[(size_t)jo * DIM4];  // L1/L2 hit (read 10 iters ago)
        sx += vn.x - vo.x; sy += vn.y - vo.y;
        sz += vn.z - vo.z; sw += vn.w - vo.w;
    }
}

extern "C" void kernel_launch(void* const* d_in, const int* in_sizes, int n_in,
                              void* d_out, int out_size, void* d_ws, size_t ws_size,
                              hipStream_t stream) {
    const float* x    = (const float*)d_in[0];   // densities (NB, DIM)
    const float* bins = (const float*)d_in[1];   // (NB,)
    float* out = (float*)d_out;

    // Scratch: partial sums (RC1*DIM floats = 4 MB) live in d_out's head —
    // consumed by k_scale before k_smooth overwrites all of d_out
    // (stream-ordered). scale (DIM floats = 128 KB) lives in d_ws.
    float* partial = out;
    float* scale   = (float*)d_ws;

    dim3 g1(DIM4 / 256, RC1);
    k_colsum<<<g1, 256, 0, stream>>>(x, partial);
    k_scale<<<DIM4 / 256, 256, 0, stream>>>(partial, bins, scale);
    dim3 g2(DIM4 / 256, RC2);
    k_smooth<<<g2, 256, 0, stream>>>(x, scale, out);
}

// Round 2
// 150.194 us; speedup vs baseline: 1.2669x; 1.2669x over previous
//
#include <hip/hip_runtime.h>

// UniformKernel: per-column (dim) moving average (K=10, replicate pad) over
// bins axis + per-column normalization. densities: (NB=2048, DIM=32768) f32.
//
// out(b,d) = window_sum(b,d) / (width * sum_i w[i]*x[i,d])
// where w[i] = # windows covering row i under edge clamping (K cancels).
//
// R2: pass-2 register ring (no x[b-4] re-read), batched 10-row load groups
// for MLP, nontemporal output stores (keep x resident in 256MB L3), RC2=32.

constexpr int NB   = 2048;
constexpr int DIM  = 32768;
constexpr int DIM4 = DIM / 4;

constexpr int RC1   = 32;        // pass-1 row chunks
constexpr int ROWS1 = NB / RC1;  // 64 rows per chunk
constexpr int RC2   = 32;        // pass-2 row chunks
constexpr int ROWS2 = NB / RC2;  // 64 rows per chunk

typedef float v4f __attribute__((ext_vector_type(4)));

__device__ __forceinline__ int clampb(int j) { return min(max(j, 0), NB - 1); }

// Weight = number of K=10 windows (PAD_LEFT=4, PAD_RIGHT=5) covering source
// row i after replicate clamping. Interior = 10; head = 15,6,7,8,9;
// tail = 9,8,7,21. Sum = NB*K = 20480.
__device__ __forceinline__ float wrow(int i) {
    int a = min(i + 4, NB - 1) - max(i - 5, 0) + 1;
    if (i == 0)      a += 10;
    if (i == NB - 1) a += 15;
    return (float)a;
}

// Pass 1: partial weighted column sums. grid (DIM4/256, RC1), 256 thr.
__global__ __launch_bounds__(256) void k_colsum(const float* __restrict__ x,
                                                float* __restrict__ partial) {
    const int d4 = blockIdx.x * 256 + threadIdx.x;
    const int r0 = blockIdx.y * ROWS1;
    const v4f* __restrict__ px = reinterpret_cast<const v4f*>(x) + d4;
    v4f acc = {0.f, 0.f, 0.f, 0.f};
    #pragma unroll 8
    for (int i = r0; i < r0 + ROWS1; ++i) {
        acc += wrow(i) * px[(size_t)i * DIM4];
    }
    reinterpret_cast<v4f*>(partial)[(size_t)blockIdx.y * DIM4 + d4] = acc;
}

// Pass 1b: reduce partials, compute scale[d] = 1/(width * sum).
__global__ __launch_bounds__(256) void k_scale(const float* __restrict__ partial,
                                               const float* __restrict__ bins,
                                               float* __restrict__ scale) {
    const int d4 = blockIdx.x * 256 + threadIdx.x;
    const v4f* __restrict__ pp = reinterpret_cast<const v4f*>(partial) + d4;
    v4f s = {0.f, 0.f, 0.f, 0.f};
    #pragma unroll
    for (int rc = 0; rc < RC1; ++rc) s += pp[(size_t)rc * DIM4];
    const float width = bins[1] - bins[0];
    v4f r;
    r.x = 1.f / (width * s.x);
    r.y = 1.f / (width * s.y);
    r.z = 1.f / (width * s.z);
    r.w = 1.f / (width * s.w);
    reinterpret_cast<v4f*>(scale)[d4] = r;
}

// Pass 2: sliding window via 10-deep register ring. Each 10-row group:
// batch-issue 10 independent loads, then 10 stores + ring update.
// window(b+1) = window(b) + x[min(b+6,NB-1)] - x[clamp(b-4)]; the subtrahend
// for row b0+t0+m is exactly what was loaded into the ring 10 rows earlier.
__global__ __launch_bounds__(256) void k_smooth(const float* __restrict__ x,
                                                const float* __restrict__ scale,
                                                float* __restrict__ out) {
    const int d4 = blockIdx.x * 256 + threadIdx.x;
    const int b0 = blockIdx.y * ROWS2;
    const v4f* __restrict__ px = reinterpret_cast<const v4f*>(x) + d4;
    v4f* __restrict__ po = reinterpret_cast<v4f*>(out) + d4;
    const v4f sc = reinterpret_cast<const v4f*>(scale)[d4];

    v4f prev[10], cur[10];
    #pragma unroll
    for (int m = 0; m < 10; ++m)
        prev[m] = px[(size_t)clampb(b0 - 4 + m) * DIM4];
    v4f S = prev[0];
    #pragma unroll
    for (int m = 1; m < 10; ++m) S += prev[m];

    constexpr int MAIN = ROWS2 - (ROWS2 % 10);  // 60
    for (int t0 = 0; t0 < MAIN; t0 += 10) {
        #pragma unroll
        for (int m = 0; m < 10; ++m)
            cur[m] = px[(size_t)min(b0 + t0 + m + 6, NB - 1) * DIM4];
        #pragma unroll
        for (int m = 0; m < 10; ++m) {
            v4f o = S * sc;
            __builtin_nontemporal_store(o, po + (size_t)(b0 + t0 + m) * DIM4);
            S += cur[m] - prev[m];
            prev[m] = cur[m];
        }
    }
    // tail (ROWS2 % 10 = 4 rows)
    #pragma unroll
    for (int m = 0; m < ROWS2 % 10; ++m)
        cur[m] = px[(size_t)min(b0 + MAIN + m + 6, NB - 1) * DIM4];
    #pragma unroll
    for (int m = 0; m < ROWS2 % 10; ++m) {
        v4f o = S * sc;
        __builtin_nontemporal_store(o, po + (size_t)(b0 + MAIN + m) * DIM4);
        S += cur[m] - prev[m];
    }
}

extern "C" void kernel_launch(void* const* d_in, const int* in_sizes, int n_in,
                              void* d_out, int out_size, void* d_ws, size_t ws_size,
                              hipStream_t stream) {
    const float* x    = (const float*)d_in[0];   // densities (NB, DIM)
    const float* bins = (const float*)d_in[1];   // (NB,)
    float* out = (float*)d_out;

    // Scratch: partial sums (RC1*DIM floats = 4 MB) in d_out's head —
    // consumed by k_scale before k_smooth overwrites d_out (stream-ordered).
    // scale (DIM floats = 128 KB) in d_ws.
    float* partial = out;
    float* scale   = (float*)d_ws;

    dim3 g1(DIM4 / 256, RC1);
    k_colsum<<<g1, 256, 0, stream>>>(x, partial);
    k_scale<<<DIM4 / 256, 256, 0, stream>>>(partial, bins, scale);
    dim3 g2(DIM4 / 256, RC2);
    k_smooth<<<g2, 256, 0, stream>>>(x, scale, out);
}